// Round 6
// baseline (6066.459 us; speedup 1.0000x reference)
//
#include <hip/hip_runtime.h>
#include <hip/hip_bf16.h>

// Problem constants
#define T_ 512
#define B_ 256
#define I_ 128
#define H_ 256
#define NB_ 16   // batch groups (16 rows each) -- independent serial chains
#define NC_ 16   // column-slice WGs per group per role (16 h-cols each)
#define PL_ 65536  // one h plane (B*H) in bf16 elems

typedef unsigned short ushort_t;
typedef __attribute__((ext_vector_type(8))) short short8;  // 8 bf16 (4 VGPRs)
typedef __attribute__((ext_vector_type(4))) float f32x4;

// d_ws layout (ushort units): h stored as 2 bf16 planes (hi/mid ~ 2^-18 rel error)
// h0: [4 bufs][2 planes][B*H]   (4-deep ring decouples L0 chain from L1 lag)
// h1: [2 bufs][2 planes][B*H]
#define OFF_H0 0
#define OFF_H1 (8 * PL_)
#define WS_USHORTS (12 * PL_)      // flags (int) at byte offset WS_USHORTS*2
// flags[0..255]    : L0 progress slots, slot[g*16+cs] = t+1 after h0[t] publish
// flags[256..511]  : L1 progress slots, slot[g*16+cs] = t+1 after h1[t] publish
// flags[1024..2047]: per-WG xcd id (g*32 + role*16 + cs)
// flags[2048..2559]: per-group arrival counters (stride 32)
#define N_FLAGS 2560

#define SPIN_MAX (1 << 18)  // normal waits are ~1e3-1e4 polls; abort fast, free-run after

__device__ __forceinline__ ushort_t f2bf(float f) {  // RNE f32->bf16
  unsigned int u = __float_as_uint(f);
  u += 0x7fffu + ((u >> 16) & 1u);
  return (ushort_t)(u >> 16);
}
__device__ __forceinline__ float bf2f(ushort_t u) {
  return __uint_as_float(((unsigned int)u) << 16);
}

// ---------------- prep: state 2-plane split + flag zeroing ----------------
__global__ void prep_kernel(const float* __restrict__ state, ushort_t* __restrict__ ws,
                            int* __restrict__ flags) {
  int i = blockIdx.x * 256 + threadIdx.x;
  if (i < 131072) {
    int tsr = i >> 16, j = i & 65535;
    float f = state[i];
    ushort_t a = f2bf(f); f -= bf2f(a);
    ushort_t b = f2bf(f);
    // init h0[-1] -> h0 buf3 ; init h1[-1] -> h1 buf1
    ushort_t* base = tsr ? (ws + OFF_H1 + 1 * (2 * PL_)) : (ws + OFF_H0 + 3 * (2 * PL_));
    base[j] = a; base[PL_ + j] = b;
  } else if (i < 131072 + N_FLAGS) {
    flags[i - 131072] = 0;
  }
}

// ---------------- fragment helpers (verified gfx950 16x16x32 layouts) ----------------
// A/B frag: element j of lane l maps to [m|n = l&15][k = (l>>4)*8 + j]
struct frag2 { short8 h, m; };

// split fp32 (16B-aligned, 8 consecutive) into 2 bf16 fragments (~2^-18 rel error)
__device__ __forceinline__ frag2 split2(const float* p) {
  f32x4 a = *(const f32x4*)p;
  f32x4 b = *(const f32x4*)(p + 4);
  float v[8] = {a[0], a[1], a[2], a[3], b[0], b[1], b[2], b[3]};
  frag2 r;
#pragma unroll
  for (int j = 0; j < 8; j++) {
    float f = v[j];
    ushort_t x = f2bf(f); f -= bf2f(x);
    ushort_t y = f2bf(f);
    r.h[j] = (short)x; r.m[j] = (short)y;
  }
  return r;
}
// weight B-frag (rows of W are output cols n): W[row + n][kc*32 + quad*8 + j]
__device__ __forceinline__ frag2 ldw2(const float* base, int ldk, int row, int kc, int lane) {
  return split2(base + (size_t)(row + (lane & 15)) * ldk + kc * 32 + ((lane >> 4) << 3));
}
// x A-frag from fp32
__device__ __forceinline__ frag2 lda_x2(const float* base, int ldk, int kc, int lane) {
  return split2(base + (size_t)(lane & 15) * ldk + kc * 32 + ((lane >> 4) << 3));
}
// L1-bypassing 16B load as 2x8B agent-relaxed atomic loads (compiler-TRACKED: proper
// vmcnt waits inserted before any use OR spill). Emits global_load_dwordx2 ... sc0.
__device__ __forceinline__ short8 ldg_sc0(const ushort_t* p) {
  const unsigned long long* q = (const unsigned long long*)p;
  unsigned long long lo = __hip_atomic_load(q,     __ATOMIC_RELAXED, __HIP_MEMORY_SCOPE_AGENT);
  unsigned long long hi = __hip_atomic_load(q + 1, __ATOMIC_RELAXED, __HIP_MEMORY_SCOPE_AGENT);
  union { unsigned long long u[2]; short8 v; } c;
  c.u[0] = lo; c.u[1] = hi;
  return c.v;
}
// one h plane A-frag
__device__ __forceinline__ short8 lda_plane(const ushort_t* plane, int gb, int kc, int lane) {
  const ushort_t* p = plane + ((size_t)gb + (lane & 15)) * H_ + kc * 32 + ((lane >> 4) << 3);
  return ldg_sc0(p);
}
__device__ __forceinline__ frag2 lda_h2(const ushort_t* bufbase, int gb, int kc, int lane) {
  frag2 r;
  r.h = lda_plane(bufbase,       gb, kc, lane);
  r.m = lda_plane(bufbase + PL_, gb, kc, lane);
  return r;
}
// zero-cost compiler fence
#define CFENCE() asm volatile("" ::: "memory")

__device__ __forceinline__ f32x4 mfma_(short8 a, short8 b, f32x4 c) {
  return __builtin_amdgcn_mfma_f32_16x16x32_bf16(a, b, c, 0, 0, 0);
}
// 2-plane split product: hh + mh + hm
__device__ __forceinline__ f32x4 macc(const frag2& A, const frag2& B, f32x4 c) {
  c = mfma_(A.h, B.h, c);
  c = mfma_(A.m, B.h, c);
  c = mfma_(A.h, B.m, c);
  return c;
}
// D frag: reg r of lane l -> row (l>>4)*4+r, col l&15 ; slot stride padded to 17
__device__ __forceinline__ void store_d(float* s, f32x4 d, int lane) {
  int c = lane & 15, q = lane >> 4;
  float* p = s + (q * 4) * 17 + c;
#pragma unroll
  for (int r = 0; r < 4; r++) p[r * 17] = d[r];
}
// Wave-parallel poll: lanes watch slots[lane&15]; wave proceeds when all >= tgt.
__device__ __forceinline__ int wavepoll1(const int* slots, int tgt, int lane, int aborted) {
  if (aborted || tgt <= 0) return aborted;
  const int* p = slots + (lane & 15);
  int n = 0;
  for (;;) {
    int v = __hip_atomic_load(p, __ATOMIC_RELAXED, __HIP_MEMORY_SCOPE_AGENT);
    if (__all(v >= tgt)) break;
    if (++n > SPIN_MAX) return 1;
  }
  return 0;
}
// Dual poll: lanes with (lane&16)==0 watch sA >= tA, others watch sB >= tB.
__device__ __forceinline__ int wavepoll2(const int* sA, int tA, const int* sB, int tB,
                                         int lane, int aborted) {
  if (aborted || (tA <= 0 && tB <= 0)) return aborted;
  const int li = lane & 15;
  const int useB = (lane & 16) != 0;
  const int* p = (useB ? sB : sA) + li;
  const int tgt = useB ? tB : tA;
  int n = 0;
  for (;;) {
    int v = (tgt <= 0) ? 0x7fffffff
                       : __hip_atomic_load(p, __ATOMIC_RELAXED, __HIP_MEMORY_SCOPE_AGENT);
    if (__all(v >= tgt)) break;
    if (++n > SPIN_MAX) return 1;
  }
  return 0;
}
__device__ __forceinline__ int get_xcc() {
  int x;
  asm volatile("s_getreg_b32 %0, hwreg(HW_REG_XCC_ID)" : "=s"(x));
  return x & 15;
}
// GRU pointwise
__device__ __forceinline__ float cellpw(float gr, float gz, float np, float h) {
  float r = 1.0f / (1.0f + expf(-gr));
  float z = 1.0f / (1.0f + expf(-gz));
  float n = tanhf(np + r * h);
  return (1.0f - z) * n + z * h;
}
// publish one thread's 2 columns of an h slice as 2 bf16 planes (packed u32 stores)
__device__ __forceinline__ void publish2(ushort_t* dst, const float* own, int sub, int gb, int cb) {
  int row = sub >> 3, cp = sub & 7;
  float v0 = own[row * 16 + cp * 2], v1 = own[row * 16 + cp * 2 + 1];
  ushort_t a0 = f2bf(v0); float r0 = v0 - bf2f(a0);
  ushort_t b0 = f2bf(r0);
  ushort_t a1 = f2bf(v1); float r1 = v1 - bf2f(a1);
  ushort_t b1 = f2bf(r1);
  size_t idx = (((size_t)(gb + row) * H_ + cb) >> 1) + cp;
  unsigned int* base = (unsigned int*)dst;
  base[idx] = (unsigned)a0 | ((unsigned)a1 << 16);
  base[(PL_ >> 1) + idx] = (unsigned)b0 | ((unsigned)b1 << 16);
}

// ---------------- persistent recurrence kernel: 512 WGs (2/CU) ----------------
// Role 0 (blocks 0..255):  L0 chain  h0[t-1] -> h0[t], ONE relay/step.
// Role 1 (blocks 256..511): L1 chain h1[t-1] -> h1[t], consumes h0[t] one step
// behind, pipelined. 4-deep h0 ring gives L0 a 3-step lead over L1 (WAR slack).
__global__ void __launch_bounds__(256, 2)
gru_main(const float* __restrict__ x,
         const float* __restrict__ Wi0, const float* __restrict__ Wh0, const float* __restrict__ Wn0,
         const float* __restrict__ Wi1, const float* __restrict__ Wh1, const float* __restrict__ Wn1,
         const float* __restrict__ state, float* __restrict__ out,
         ushort_t* __restrict__ ws, int* __restrict__ flags) {
  __shared__ float sP[8][16][17];  // MFMA partial-sum slots
  __shared__ float hown[256];      // this WG's fp32 h-slice carry (h0 or h1 per role)
  __shared__ int s_fast;

  const int tid = (int)threadIdx.x;
  const int lane = tid & 63;
  const int w = tid >> 6;                    // wave id 0..3
  const int b = (int)blockIdx.x;
  const int g = b & 15;                      // batch group (same XCD for all 32 WGs: b%8==g%8)
  const int cs = (b >> 4) & 15;              // column slice
  const int role = b >> 8;                   // 0 = L0 chain, 1 = L1 chain
  const int gb = g * 16;                     // batch row base
  const int cb = cs * 16;                    // h-col base

  ushort_t* h0sh = ws + OFF_H0;
  ushort_t* h1sh = ws + OFF_H1;
  int* slots0 = flags + g * 16;              // L0 progress (one 64B line per group)
  int* slots1 = flags + 256 + g * 16;        // L1 progress
  int* myslot = (role ? slots1 : slots0) + cs;
  int* xarr = flags + 1024;
  int* actr = flags + 2048 + g * 32;

  const int pm = tid >> 4;  // pointwise row (batch)
  const int pc = tid & 15;  // pointwise col

  hown[tid] = state[(size_t)role * B_ * H_ + (size_t)(gb + pm) * H_ + cb + pc];

  // ---- one-time group XCD-locality check: all 32 WGs of group on one XCD? ----
  if (tid == 0) {
    int myx = get_xcc();
    __hip_atomic_store(&xarr[g * 32 + role * 16 + cs], myx, __ATOMIC_RELAXED,
                       __HIP_MEMORY_SCOPE_AGENT);
    __threadfence();
    __hip_atomic_fetch_add(actr, 1, __ATOMIC_RELEASE, __HIP_MEMORY_SCOPE_AGENT);
    int n = 0, ab = 0;
    while (__hip_atomic_load(actr, __ATOMIC_RELAXED, __HIP_MEMORY_SCOPE_AGENT) < 2 * NC_) {
      if (++n > SPIN_MAX) { ab = 1; break; }
    }
    __threadfence();
    int f = ab ? 0 : 1;
    if (!ab) {
#pragma unroll
      for (int i = 0; i < 2 * NC_; i++)
        f &= (__hip_atomic_load(&xarr[g * 32 + i], __ATOMIC_RELAXED,
                                __HIP_MEMORY_SCOPE_AGENT) == myx);
    }
    s_fast = f;
  }

  // Stationary weight B-fragments (each role holds only its half).
  // Role0: w0: r x(F0-3)+h k0-3(F4-7); w1: r h k4-7(F0-3)+npre(F4-7);
  //        w2: z x+h k0-3;             w3: z h k4-7(F0-3)
  // Role1: w0: r Q-side; w1: r R-side; w2: z Q; w3: z R; n1 2 chunks each (G8,G9)
  frag2 F2[8], G2[10];
  if (role == 0) {
    if (w == 0) {
#pragma unroll
      for (int kc = 0; kc < 4; kc++) F2[kc] = ldw2(Wi0, I_, cb, kc, lane);
#pragma unroll
      for (int kc = 0; kc < 4; kc++) F2[4 + kc] = ldw2(Wh0, H_, cb, kc, lane);
    } else if (w == 1) {
#pragma unroll
      for (int kc = 0; kc < 4; kc++) F2[kc] = ldw2(Wh0, H_, cb, 4 + kc, lane);
#pragma unroll
      for (int kc = 0; kc < 4; kc++) F2[4 + kc] = ldw2(Wn0, I_, cb, kc, lane);
    } else if (w == 2) {
#pragma unroll
      for (int kc = 0; kc < 4; kc++) F2[kc] = ldw2(Wi0, I_, 256 + cb, kc, lane);
#pragma unroll
      for (int kc = 0; kc < 4; kc++) F2[4 + kc] = ldw2(Wh0, H_, 256 + cb, kc, lane);
    } else {
#pragma unroll
      for (int kc = 0; kc < 4; kc++) F2[kc] = ldw2(Wh0, H_, 256 + cb, 4 + kc, lane);
    }
  } else {
    if (w == 0) {
#pragma unroll
      for (int kc = 0; kc < 8; kc++) G2[kc] = ldw2(Wi1, H_, cb, kc, lane);
      G2[8] = ldw2(Wn1, H_, cb, 0, lane); G2[9] = ldw2(Wn1, H_, cb, 1, lane);
    } else if (w == 1) {
#pragma unroll
      for (int kc = 0; kc < 8; kc++) G2[kc] = ldw2(Wh1, H_, cb, kc, lane);
      G2[8] = ldw2(Wn1, H_, cb, 2, lane); G2[9] = ldw2(Wn1, H_, cb, 3, lane);
    } else if (w == 2) {
#pragma unroll
      for (int kc = 0; kc < 8; kc++) G2[kc] = ldw2(Wi1, H_, 256 + cb, kc, lane);
      G2[8] = ldw2(Wn1, H_, cb, 4, lane); G2[9] = ldw2(Wn1, H_, cb, 5, lane);
    } else {
#pragma unroll
      for (int kc = 0; kc < 8; kc++) G2[kc] = ldw2(Wh1, H_, 256 + cb, kc, lane);
      G2[8] = ldw2(Wn1, H_, cb, 6, lane); G2[9] = ldw2(Wn1, H_, cb, 7, lane);
    }
  }

  __syncthreads();
  const int fast = s_fast;

  int aborted = 0;
  const f32x4 zz = {0.f, 0.f, 0.f, 0.f};

  if (role == 0) {
    //================= L0 chain: one relay per step =================
    for (int t = 0; t < T_; t++) {
      const float* xt = x + ((size_t)t * B_ + gb) * I_;
      f32x4 g0 = zz, g1 = zz, n0 = zz, n1 = zz;
      // x-part MFMAs: independent of peers, overlap the poll
      if (w == 0 || w == 2) {
#pragma unroll
        for (int kc = 0; kc < 4; kc++) {
          frag2 a = lda_x2(xt, I_, kc, lane);
          if (kc & 1) g1 = macc(a, F2[kc], g1); else g0 = macc(a, F2[kc], g0);
        }
      } else if (w == 1) {
#pragma unroll
        for (int kc = 0; kc < 4; kc++) {
          frag2 a = lda_x2(xt, I_, kc, lane);
          if (kc & 1) n1 = macc(a, F2[4 + kc], n1); else n0 = macc(a, F2[4 + kc], n0);
        }
      }
      // h0[t-1] ready (slots0 >= t) + h0-ring WAR vs L1 readers (slots1 >= t-3)
      aborted = wavepoll2(slots0, t, slots1, t - 3, lane, aborted);
      if (!fast) __threadfence();
      CFENCE();
      {
        const ushort_t* P = h0sh + (size_t)((t + 3) & 3) * 2 * PL_;  // h0[t-1]
        if (w == 0 || w == 2) {
#pragma unroll
          for (int kc = 0; kc < 4; kc++) {
            frag2 a = lda_h2(P, gb, kc, lane);
            if (kc & 1) g1 = macc(a, F2[4 + kc], g1); else g0 = macc(a, F2[4 + kc], g0);
          }
        } else {
#pragma unroll
          for (int kc = 0; kc < 4; kc++) {
            frag2 a = lda_h2(P, gb, 4 + kc, lane);
            if (kc & 1) g1 = macc(a, F2[kc], g1); else g0 = macc(a, F2[kc], g0);
          }
        }
      }
      store_d(&sP[w][0][0], g0 + g1, lane);
      if (w == 1) store_d(&sP[4][0][0], n0 + n1, lane);
      __syncthreads();
      {
        float gr = sP[0][pm][pc] + sP[1][pm][pc];
        float gz = sP[2][pm][pc] + sP[3][pm][pc];
        float np = sP[4][pm][pc];
        hown[tid] = cellpw(gr, gz, np, hown[tid]);
      }
      __syncthreads();
      if (tid < 128) publish2(h0sh + (size_t)(t & 3) * 2 * PL_, hown, tid, gb, cb);
      __syncthreads();  // vmcnt(0) drained -> stores visible in local L2
      if (tid == 0) {
        if (!fast) __threadfence();
        __hip_atomic_store(myslot, t + 1, __ATOMIC_RELAXED, __HIP_MEMORY_SCOPE_AGENT);
      }
    }
    out[(size_t)T_ * B_ * H_ + (size_t)(gb + pm) * H_ + cb + pc] = hown[tid];
  } else {
    //================= L1 chain: one relay per step (lags L0 by ~1) =================
    for (int t = 0; t < T_; t++) {
      // own chain first: h1[t-1] ready + h1 WAR (slots1 >= t)
      aborted = wavepoll1(slots1, t, lane, aborted);
      if (!fast) __threadfence();
      CFENCE();
      f32x4 a0v = zz, a1v = zz, nn = zz;
      const ushort_t* Rb = h1sh + (size_t)((t + 1) & 1) * 2 * PL_;  // h1[t-1]
      if (w == 1 || w == 3) {
        // R-side MFMAs before h0[t] is even ready: off the relay path
#pragma unroll
        for (int kc = 0; kc < 8; kc++) {
          frag2 a = lda_h2(Rb, gb, kc, lane);
          if (kc & 1) a1v = macc(a, G2[kc], a1v); else a0v = macc(a, G2[kc], a0v);
        }
      }
      // now h0[t] (slots0 >= t+1)
      aborted = wavepoll1(slots0, t + 1, lane, aborted);
      if (!fast) __threadfence();
      CFENCE();
      const ushort_t* Qb = h0sh + (size_t)(t & 3) * 2 * PL_;        // h0[t]
      if (w == 0 || w == 2) {
        const int nb = (w == 0) ? 0 : 4;
#pragma unroll
        for (int kc = 0; kc < 8; kc++) {
          frag2 a = lda_h2(Qb, gb, kc, lane);
          if (kc & 1) a1v = macc(a, G2[kc], a1v); else a0v = macc(a, G2[kc], a0v);
          if (kc == nb)     nn = macc(a, G2[8], nn);
          if (kc == nb + 1) nn = macc(a, G2[9], nn);
        }
      } else {
        const int nb = (w == 1) ? 2 : 6;
        nn = macc(lda_h2(Qb, gb, nb, lane), G2[8], nn);
        nn = macc(lda_h2(Qb, gb, nb + 1, lane), G2[9], nn);
      }
      store_d(&sP[w][0][0], a0v + a1v, lane);
      store_d(&sP[4 + w][0][0], nn, lane);
      __syncthreads();
      float hn;
      {
        float gr = sP[0][pm][pc] + sP[1][pm][pc];
        float gz = sP[2][pm][pc] + sP[3][pm][pc];
        float np = sP[4][pm][pc] + sP[5][pm][pc] + sP[6][pm][pc] + sP[7][pm][pc];
        hn = cellpw(gr, gz, np, hown[tid]);
        hown[tid] = hn;
      }
      __syncthreads();
      if (tid < 128) publish2(h1sh + (size_t)(t & 1) * 2 * PL_, hown, tid, gb, cb);
      __syncthreads();  // vmcnt(0) drained -> publish visible
      if (tid == 0) {
        if (!fast) __threadfence();
        __hip_atomic_store(myslot, t + 1, __ATOMIC_RELAXED, __HIP_MEMORY_SCOPE_AGENT);
      }
      // out[t] HBM store AFTER the bump: store-ack off the relay critical path
      out[((size_t)t * B_ + gb + pm) * H_ + cb + pc] = hn;
    }
    out[(size_t)T_ * B_ * H_ + (size_t)B_ * H_ + (size_t)(gb + pm) * H_ + cb + pc] = hown[tid];
  }

  // diagnostic sentinel: 4096 => spin abort (deadlock signature)
  if (tid == 0 && aborted) out[(size_t)gb * H_ + cb] = 4096.0f;
}

extern "C" void kernel_launch(void* const* d_in, const int* in_sizes, int n_in,
                              void* d_out, int out_size, void* d_ws, size_t ws_size,
                              hipStream_t stream) {
  const float* x     = (const float*)d_in[0];
  const float* state = (const float*)d_in[1];
  const float* Wi0   = (const float*)d_in[2];
  const float* Wh0   = (const float*)d_in[3];
  const float* Wn0   = (const float*)d_in[4];
  const float* Wi1   = (const float*)d_in[5];
  const float* Wh1   = (const float*)d_in[6];
  const float* Wn1   = (const float*)d_in[7];
  float* out = (float*)d_out;
  ushort_t* ws = (ushort_t*)d_ws;
  int* flags = (int*)((char*)d_ws + (size_t)WS_USHORTS * 2);

  prep_kernel<<<dim3((131072 + N_FLAGS + 255) / 256), dim3(256), 0, stream>>>(state, ws, flags);

  gru_main<<<dim3(2 * NB_ * NC_), dim3(256), 0, stream>>>(
      x, Wi0, Wh0, Wn0, Wi1, Wh1, Wn1, state, out, ws, flags);
}